// Round 1
// baseline (660.240 us; speedup 1.0000x reference)
//
#include <hip/hip_runtime.h>

#define SS 128
#define S3 (SS*SS*SS)
#define NBATCH 4
#define LEAK 0.01f
#define BNEPS 1e-4f

// ---------------- workspace layout (bytes) ----------------
constexpr size_t OFF_DENSE    = 0;                                   // f32 [4][128^3]   33.5MB (zeroed)
constexpr size_t OFF_MASKBITS = OFF_DENSE + (size_t)NBATCH*S3*4;     // u32 bitgrid       1MB  (zeroed)
constexpr size_t OFF_MASK32   = OFF_MASKBITS + (size_t)NBATCH*S3/8;  // u8 [4][32^3]    128KB  (zeroed)
constexpr size_t OFF_MASK8    = OFF_MASK32 + (size_t)NBATCH*32768;   // u8 [4][8^3]       2KB  (zeroed)
constexpr size_t OFF_X1       = OFF_MASK8 + (size_t)NBATCH*512;      // f32 [4][8][32^3]  4MB  (zeroed, atomic acc)
constexpr size_t OFF_STATS    = OFF_X1 + (size_t)NBATCH*8*32768*4;   // f32 [64]               (zeroed)
constexpr size_t OFF_COUNT    = OFF_STATS + 256;                     // u32 count              (zeroed)
constexpr size_t ZERO_BYTES   = OFF_COUNT + 16;                      // everything above zeroed each launch
constexpr size_t OFF_X2       = ZERO_BYTES;                          // f32 [4][16][8^3] 128KB (fully overwritten)
constexpr size_t OFF_X3       = OFF_X2 + (size_t)NBATCH*16*512*4;    // f32 [4][32][2^3]  4KB  (fully overwritten)
constexpr size_t OFF_LIST     = OFF_X3 + (size_t)NBATCH*32*8*4;      // u32 [262144] occupied voxel list
constexpr size_t OFF_X0L      = OFF_LIST + 262144*4;                 // f32 [262144][4] conv0 outputs

// stats slots: [0..3] sum1, [4..7] sumsq1, [8] cnt2, [9..16] sum2, [17..24] sumsq2,
//              [25] cnt8, [26..41] sum3, [42..57] sumsq3

__device__ inline float waveSum(float v) {
#pragma unroll
    for (int off = 32; off; off >>= 1) v += __shfl_xor(v, off, 64);
    return v;
}

// -------- zero the accumulator region --------
__global__ void k_zero(float4* __restrict__ p, size_t n16) {
    size_t i = (size_t)blockIdx.x * blockDim.x + threadIdx.x;
    size_t stride = (size_t)gridDim.x * blockDim.x;
    for (; i < n16; i += stride) p[i] = make_float4(0.f, 0.f, 0.f, 0.f);
}

// -------- scatter points; dedup via bit grid; build occupied list + coarse masks --------
__global__ void k_scatter(const float* __restrict__ pc, float* __restrict__ dense,
                          unsigned* __restrict__ maskbits, unsigned char* __restrict__ mask32,
                          unsigned char* __restrict__ mask8, unsigned* __restrict__ list,
                          unsigned* __restrict__ count, int n) {
    int i = blockIdx.x * blockDim.x + threadIdx.x;
    if (i >= n) return;
    float c0 = pc[i*5+0], c1 = pc[i*5+1], c2 = pc[i*5+2], cb = pc[i*5+3], f = pc[i*5+4];
    int d = (int)c0, h = (int)c1, w = (int)c2, b = (int)cb;
    unsigned vox = (((unsigned)b*SS + d)*SS + h)*SS + w;
    atomicAdd(&dense[vox], f);
    unsigned bit = 1u << (vox & 31);
    unsigned old = atomicOr(&maskbits[vox >> 5], bit);
    if (!(old & bit)) {
        unsigned pos = atomicAdd(count, 1u);
        list[pos] = vox;
        mask32[b*32768 + (d>>2)*1024 + (h>>2)*32 + (w>>2)] = 1;
        mask8 [b*512   + (d>>4)*64   + (h>>4)*8  + (w>>4)] = 1;
    }
}

// -------- conv0 (3x3x3 SAME) at occupied voxels + BN1 statistics --------
__global__ void k_conv0_stats(const float* __restrict__ dense, const unsigned* __restrict__ list,
                              const unsigned* __restrict__ count, const float* __restrict__ w0,
                              float* __restrict__ x0l, float* __restrict__ stats) {
    __shared__ float ws[108];
    if (threadIdx.x < 108) ws[threadIdx.x] = w0[threadIdx.x];
    __syncthreads();
    int i = blockIdx.x * blockDim.x + threadIdx.x;
    unsigned cnt = *count;
    float a0=0.f, a1=0.f, a2=0.f, a3=0.f;
    if (i < (int)cnt) {
        unsigned vox = list[i];
        int w = vox & 127, h = (vox>>7)&127, d = (vox>>14)&127, b = (int)(vox>>21);
        const float* dn = dense + (size_t)b * S3;
        for (int dz=-1; dz<=1; ++dz) {
            int zz = d+dz; if ((unsigned)zz >= SS) continue;
            for (int dy=-1; dy<=1; ++dy) {
                int yy = h+dy; if ((unsigned)yy >= SS) continue;
                for (int dx=-1; dx<=1; ++dx) {
                    int xx = w+dx; if ((unsigned)xx >= SS) continue;
                    float v = dn[(zz*SS + yy)*SS + xx];
                    int kk = (dz+1)*9 + (dy+1)*3 + (dx+1);
                    a0 += v*ws[kk]; a1 += v*ws[27+kk]; a2 += v*ws[54+kk]; a3 += v*ws[81+kk];
                }
            }
        }
        x0l[i*4+0]=a0; x0l[i*4+1]=a1; x0l[i*4+2]=a2; x0l[i*4+3]=a3;
    }
    float s[8] = {a0,a1,a2,a3, a0*a0,a1*a1,a2*a2,a3*a3};
#pragma unroll
    for (int k=0;k<8;++k) {
        float r = waveSum(s[k]);
        if ((threadIdx.x & 63) == 0) atomicAdd(&stats[k], r);
    }
}

// -------- BN1 + LeakyReLU + stride-2 conv + pool/8, scattered into x1 (32^3) --------
__global__ void k_stage1(const float* __restrict__ x0l, const unsigned* __restrict__ list,
                         const unsigned* __restrict__ count, const float* __restrict__ g1,
                         const float* __restrict__ b1, const float* __restrict__ wc1,
                         const float* __restrict__ stats, float* __restrict__ x1) {
    __shared__ float wsh[256];
    __shared__ float sc[4], sh[4];
    if (threadIdx.x < 256) wsh[threadIdx.x] = wc1[threadIdx.x];
    if (threadIdx.x < 4) {
        int c = threadIdx.x;
        float cnt = fmaxf((float)(*count), 1.0f);
        float mean = stats[c] / cnt;
        float var  = stats[4+c] / cnt - mean*mean;
        float s = g1[c] * rsqrtf(var + BNEPS);
        sc[c] = s; sh[c] = b1[c] - mean*s;
    }
    __syncthreads();
    int i = blockIdx.x * blockDim.x + threadIdx.x;
    unsigned cnt = *count;
    if (i >= (int)cnt) return;
    unsigned vox = list[i];
    int w = vox & 127, h = (vox>>7)&127, d = (vox>>14)&127, b = (int)(vox>>21);
    float y[4];
#pragma unroll
    for (int c=0;c<4;++c) { float t = x0l[i*4+c]*sc[c] + sh[c]; y[c] = (t >= 0.f) ? t : LEAK*t; }
    int widx = (d&1)*4 + (h&1)*2 + (w&1);
    int s32  = (d>>2)*1024 + (h>>2)*32 + (w>>2);
    float* dst = x1 + (size_t)b*8*32768 + s32;
#pragma unroll
    for (int o=0;o<8;++o) {
        const float* wp = wsh + o*32 + widx;
        float contrib = y[0]*wp[0] + y[1]*wp[8] + y[2]*wp[16] + y[3]*wp[24];
        atomicAdd(dst + o*32768, contrib * 0.125f);
    }
}

// -------- stage-2 stats: per-channel sums of x1 + mask32 count --------
__global__ void k_stage2_stats(const float* __restrict__ x1, const unsigned char* __restrict__ mask32,
                               float* __restrict__ stats) {
    int blk = blockIdx.x;
    if (blk < 32) { // plane b*8+c
        const float* p = x1 + (size_t)blk * 32768;
        float s=0.f, sq=0.f;
        for (int i = threadIdx.x; i < 32768; i += blockDim.x) { float v = p[i]; s += v; sq += v*v; }
        s = waveSum(s); sq = waveSum(sq);
        if ((threadIdx.x & 63) == 0) {
            int c = blk & 7;
            atomicAdd(&stats[9 + c], s);
            atomicAdd(&stats[17 + c], sq);
        }
    } else {        // mask count, batch b
        int b = blk - 32;
        const unsigned char* m = mask32 + b*32768;
        float s = 0.f;
        for (int i = threadIdx.x; i < 32768; i += blockDim.x) s += (float)m[i];
        s = waveSum(s);
        if ((threadIdx.x & 63) == 0) atomicAdd(&stats[8], s);
    }
}

// -------- stage 2: BN2+LReLU+mask, 2x2x2 stride2 conv (8->16), pool/8 -> x2 (8^3) --------
__global__ void k_stage2(const float* __restrict__ x1, const unsigned char* __restrict__ mask32,
                         const float* __restrict__ g2, const float* __restrict__ b2,
                         const float* __restrict__ wc2, const float* __restrict__ stats,
                         float* __restrict__ x2) {
    __shared__ float wsh[1024];
    for (int i = threadIdx.x; i < 1024; i += blockDim.x) wsh[i] = wc2[i];
    float sc[8], sh[8];
    float cnt = fmaxf(stats[8], 1.0f);
#pragma unroll
    for (int c=0;c<8;++c) {
        float mean = stats[9+c] / cnt;
        float var  = stats[17+c] / cnt - mean*mean;
        float s = g2[c] * rsqrtf(var + BNEPS);
        sc[c] = s; sh[c] = b2[c] - mean*s;
    }
    __syncthreads();
    int t = blockIdx.x * blockDim.x + threadIdx.x;  // [0, 32768) = ((b*16+o)*512)+r
    int r = t & 511, bo = t >> 9;
    int o = bo & 15, b = bo >> 4;
    int d8 = r >> 6, h8 = (r >> 3) & 7, w8 = r & 7;
    const float* xb = x1 + (size_t)b*8*32768;
    const unsigned char* mb = mask32 + b*32768;
    float acc = 0.f;
    for (int dd=0; dd<4; ++dd) for (int hh=0; hh<4; ++hh) for (int ww=0; ww<4; ++ww) {
        int s32 = ((d8*4+dd) << 10) + ((h8*4+hh) << 5) + (w8*4+ww);
        if (!mb[s32]) continue;
        int widx = (dd&1)*4 + (hh&1)*2 + (ww&1);
        const float* wp = wsh + o*64 + widx;
#pragma unroll
        for (int c=0;c<8;++c) {
            float v = xb[c*32768 + s32];
            float tt = v*sc[c] + sh[c];
            tt = (tt >= 0.f) ? tt : LEAK*tt;
            acc += tt * wp[c*8];
        }
    }
    x2[t] = acc * 0.125f;
}

// -------- stage-3 stats --------
__global__ void k_stage3_stats(const float* __restrict__ x2, const unsigned char* __restrict__ mask8,
                               float* __restrict__ stats) {
    int blk = blockIdx.x;
    if (blk < 64) { // plane b*16+c
        const float* p = x2 + (size_t)blk * 512;
        float s=0.f, sq=0.f;
        for (int i = threadIdx.x; i < 512; i += blockDim.x) { float v = p[i]; s += v; sq += v*v; }
        s = waveSum(s); sq = waveSum(sq);
        if ((threadIdx.x & 63) == 0) {
            int c = blk & 15;
            atomicAdd(&stats[26 + c], s);
            atomicAdd(&stats[42 + c], sq);
        }
    } else {
        int b = blk - 64;
        const unsigned char* m = mask8 + b*512;
        float s = 0.f;
        for (int i = threadIdx.x; i < 512; i += blockDim.x) s += (float)m[i];
        s = waveSum(s);
        if ((threadIdx.x & 63) == 0) atomicAdd(&stats[25], s);
    }
}

// -------- stage 3: BN3+LReLU+mask, conv (16->32), pool/8 -> x3 (2^3) --------
__global__ void k_stage3(const float* __restrict__ x2, const unsigned char* __restrict__ mask8,
                         const float* __restrict__ g3, const float* __restrict__ b3,
                         const float* __restrict__ wc3, const float* __restrict__ stats,
                         float* __restrict__ x3) {
    __shared__ float wsh[4096];
    for (int i = threadIdx.x; i < 4096; i += blockDim.x) wsh[i] = wc3[i];
    float sc[16], sh[16];
    float cnt = fmaxf(stats[25], 1.0f);
#pragma unroll
    for (int c=0;c<16;++c) {
        float mean = stats[26+c] / cnt;
        float var  = stats[42+c] / cnt - mean*mean;
        float s = g3[c] * rsqrtf(var + BNEPS);
        sc[c] = s; sh[c] = b3[c] - mean*s;
    }
    __syncthreads();
    int t = blockIdx.x * blockDim.x + threadIdx.x;  // [0,1024) = ((b*32+o)*8)+r
    int r = t & 7, bo = t >> 3;
    int o = bo & 31, b = bo >> 5;
    int d2 = (r >> 2) & 1, h2 = (r >> 1) & 1, w2 = r & 1;
    const float* xb = x2 + (size_t)b*16*512;
    const unsigned char* mb = mask8 + b*512;
    float acc = 0.f;
    for (int dd=0; dd<4; ++dd) for (int hh=0; hh<4; ++hh) for (int ww=0; ww<4; ++ww) {
        int s8 = (d2*4+dd)*64 + (h2*4+hh)*8 + (w2*4+ww);
        if (!mb[s8]) continue;
        int widx = (dd&1)*4 + (hh&1)*2 + (ww&1);
        const float* wp = wsh + o*128 + widx;
#pragma unroll
        for (int c=0;c<16;++c) {
            float v = xb[c*512 + s8];
            float tt = v*sc[c] + sh[c];
            tt = (tt >= 0.f) ? tt : LEAK*tt;
            acc += tt * wp[c*8];
        }
    }
    x3[t] = acc * 0.125f;
}

// -------- final linear: (4,256) @ (256,64)^T + blin --------
__global__ void k_linear(const float* __restrict__ x3, const float* __restrict__ wlin,
                         const float* __restrict__ blin, float* __restrict__ out) {
    int t = threadIdx.x;           // [0,256)
    int b = t >> 6, j = t & 63;
    float acc = blin[j];
    const float* xb = x3 + b*256;
    const float* wj = wlin + j*256;
#pragma unroll 8
    for (int k=0;k<256;++k) acc += xb[k] * wj[k];
    out[b*64 + j] = acc;
}

extern "C" void kernel_launch(void* const* d_in, const int* in_sizes, int n_in,
                              void* d_out, int out_size, void* d_ws, size_t ws_size,
                              hipStream_t stream) {
    const float* pc   = (const float*)d_in[0];
    const float* w0   = (const float*)d_in[1];
    const float* g1   = (const float*)d_in[2];
    const float* b1   = (const float*)d_in[3];
    const float* wc1  = (const float*)d_in[4];
    const float* g2   = (const float*)d_in[5];
    const float* b2   = (const float*)d_in[6];
    const float* wc2  = (const float*)d_in[7];
    const float* g3   = (const float*)d_in[8];
    const float* b3   = (const float*)d_in[9];
    const float* wc3  = (const float*)d_in[10];
    const float* wlin = (const float*)d_in[11];
    const float* blin = (const float*)d_in[12];
    float* out = (float*)d_out;

    char* ws = (char*)d_ws;
    float*         dense    = (float*)(ws + OFF_DENSE);
    unsigned*      maskbits = (unsigned*)(ws + OFF_MASKBITS);
    unsigned char* mask32   = (unsigned char*)(ws + OFF_MASK32);
    unsigned char* mask8    = (unsigned char*)(ws + OFF_MASK8);
    float*         x1       = (float*)(ws + OFF_X1);
    float*         stats    = (float*)(ws + OFF_STATS);
    unsigned*      count    = (unsigned*)(ws + OFF_COUNT);
    float*         x2       = (float*)(ws + OFF_X2);
    float*         x3       = (float*)(ws + OFF_X3);
    unsigned*      list     = (unsigned*)(ws + OFF_LIST);
    float*         x0l      = (float*)(ws + OFF_X0L);

    int n = in_sizes[0] / 5;
    int nb = (n + 255) / 256;

    k_zero<<<2048, 256, 0, stream>>>((float4*)ws, ZERO_BYTES / 16);
    k_scatter<<<nb, 256, 0, stream>>>(pc, dense, maskbits, mask32, mask8, list, count, n);
    k_conv0_stats<<<nb, 256, 0, stream>>>(dense, list, count, w0, x0l, stats);
    k_stage1<<<nb, 256, 0, stream>>>(x0l, list, count, g1, b1, wc1, stats, x1);
    k_stage2_stats<<<36, 256, 0, stream>>>(x1, mask32, stats);
    k_stage2<<<128, 256, 0, stream>>>(x1, mask32, g2, b2, wc2, stats, x2);
    k_stage3_stats<<<68, 256, 0, stream>>>(x2, mask8, stats);
    k_stage3<<<4, 256, 0, stream>>>(x2, mask8, g3, b3, wc3, stats, x3);
    k_linear<<<1, 256, 0, stream>>>(x3, wlin, blin, out);
}

// Round 6
// 428.159 us; speedup vs baseline: 1.5420x; 1.5420x over previous
//
#include <hip/hip_runtime.h>

#define SS 128
#define S3 (SS*SS*SS)
#define NBATCH 4
#define LEAK 0.01f
#define BNEPS 1e-4f
#define NTILE 16384          // 4 batches * 16^3 tiles of 8^3
#define MAXSLOT 64

// ---------------- workspace layout (bytes) ----------------
constexpr size_t OFF_DENSE    = 0;                                   // f32 [4][128^3]   33.5MB (zeroed)
constexpr size_t OFF_MASKBITS = OFF_DENSE + (size_t)NBATCH*S3*4;     // u32 bitgrid       1MB  (zeroed)
constexpr size_t OFF_MASK32   = OFF_MASKBITS + (size_t)NBATCH*S3/8;  // u8 [4][32^3]    128KB  (zeroed)
constexpr size_t OFF_MASK8    = OFF_MASK32 + (size_t)NBATCH*32768;   // u8 [4][8^3]       2KB  (zeroed)
constexpr size_t OFF_X1       = OFF_MASK8 + (size_t)NBATCH*512;      // f32 [4][8][32^3]  4MB  (zeroed, atomic acc)
constexpr size_t OFF_STATS    = OFF_X1 + (size_t)NBATCH*8*32768*4;   // f32 [64]               (zeroed)
constexpr size_t ZERO_BYTES   = OFF_STATS + 256;
constexpr size_t OFF_NBLK     = ZERO_BYTES;                          // u32 [16384] per-tile count (overwritten)
constexpr size_t OFF_LIST     = OFF_NBLK + NTILE*4;                  // u32 [16384][64] vox ids
constexpr size_t OFF_X0L      = OFF_LIST + (size_t)NTILE*MAXSLOT*4;  // f32x4 [16384][64] conv0 out
constexpr size_t OFF_X2       = OFF_X0L + (size_t)NTILE*MAXSLOT*16;  // f32 [4][16][8^3] 128KB
constexpr size_t OFF_X3       = OFF_X2 + (size_t)NBATCH*16*512*4;    // f32 [4][32][2^3]  4KB

// stats slots: [0..3] sum1, [4..7] sumsq1, [8] cnt2, [9..16] sum2, [17..24] sumsq2,
//              [25] cnt8, [26..41] sum3, [42..57] sumsq3, [58] cnt1

__device__ inline float waveSum(float v) {
#pragma unroll
    for (int off = 32; off; off >>= 1) v += __shfl_xor(v, off, 64);
    return v;
}

// -------- scatter points; dedup via bit grid; coarse masks --------
__global__ void k_scatter(const float* __restrict__ pc, float* __restrict__ dense,
                          unsigned* __restrict__ maskbits, unsigned char* __restrict__ mask32,
                          unsigned char* __restrict__ mask8, int n) {
    int i = blockIdx.x * blockDim.x + threadIdx.x;
    if (i >= n) return;
    float c0 = pc[i*5+0], c1 = pc[i*5+1], c2 = pc[i*5+2], cb = pc[i*5+3], f = pc[i*5+4];
    int d = (int)c0, h = (int)c1, w = (int)c2, b = (int)cb;
    unsigned vox = (((unsigned)b*SS + d)*SS + h)*SS + w;
    atomicAdd(&dense[vox], f);
    atomicOr(&maskbits[vox >> 5], 1u << (vox & 31));
    mask32[b*32768 + (d>>2)*1024 + (h>>2)*32 + (w>>2)] = 1;
    mask8 [b*512   + (d>>4)*64   + (h>>4)*8  + (w>>4)] = 1;
}

// -------- dense tiled conv0 (3x3x3 SAME) + deterministic compaction --------
__global__ __launch_bounds__(512) void k_conv0(const float* __restrict__ dense,
                                               const unsigned* __restrict__ maskbits,
                                               const float* __restrict__ w0g,
                                               unsigned* __restrict__ nblk,
                                               unsigned* __restrict__ list,
                                               float4* __restrict__ x0l) {
    __shared__ float tile[1000];   // 10x10x10 halo tile
    __shared__ float ws[108];
    __shared__ unsigned wtot[8];
    int tid = threadIdx.x;
    int tw = blockIdx.x, th = blockIdx.y, tzb = blockIdx.z;   // tzb = b*16 + d-tile
    int b = tzb >> 4, td = tzb & 15;
    int d0 = td*8, h0 = th*8, wo = tw*8;
    if (tid < 108) ws[tid] = w0g[tid];
    const float* dn = dense + (size_t)b * S3;
    for (int i = tid; i < 1000; i += 512) {
        int dz = i/100, rem = i - dz*100, dy = rem/10, dx = rem - dy*10;
        int gz = d0-1+dz, gy = h0-1+dy, gx = wo-1+dx;
        float v = 0.f;
        if ((unsigned)gz < SS && (unsigned)gy < SS && (unsigned)gx < SS)
            v = dn[((size_t)gz*SS + gy)*SS + gx];
        tile[i] = v;
    }
    __syncthreads();
    int tz = tid >> 6, ty = (tid >> 3) & 7, tx = tid & 7;
    int gz = d0+tz, gy = h0+ty, gx = wo+tx;
    unsigned vox = (((unsigned)b*SS + gz)*SS + gy)*SS + gx;
    bool occ = (maskbits[vox >> 5] >> (vox & 31)) & 1u;
    float a0=0.f, a1=0.f, a2=0.f, a3=0.f;
    if (occ) {
#pragma unroll
        for (int kd=0; kd<3; ++kd)
#pragma unroll
            for (int kh=0; kh<3; ++kh)
#pragma unroll
                for (int kw=0; kw<3; ++kw) {
                    float v = tile[(tz+kd)*100 + (ty+kh)*10 + (tx+kw)];
                    int kk = kd*9 + kh*3 + kw;
                    a0 += v*ws[kk]; a1 += v*ws[27+kk]; a2 += v*ws[54+kk]; a3 += v*ws[81+kk];
                }
    }
    unsigned long long ball = __ballot(occ);
    int lane = tid & 63, wid = tid >> 6;
    if (lane == 0) wtot[wid] = __popcll(ball);
    __syncthreads();
    unsigned base = 0, total = 0;
#pragma unroll
    for (int j=0;j<8;++j) { unsigned t = wtot[j]; if (j < wid) base += t; total += t; }
    int blk = (tzb*16 + th)*16 + tw;
    if (tid == 0) nblk[blk] = total < MAXSLOT ? total : MAXSLOT;
    if (occ) {
        unsigned pos = base + __popcll(ball & ((1ull << lane) - 1ull));
        if (pos < MAXSLOT) {
            list[(size_t)blk*MAXSLOT + pos] = vox;
            x0l[(size_t)blk*MAXSLOT + pos] = make_float4(a0, a1, a2, a3);
        }
    }
}

// -------- BN1 statistics over compacted conv0 output --------
__global__ void k_stats1(const float4* __restrict__ x0l, const unsigned* __restrict__ nblk,
                         float* __restrict__ stats) {
    int tid0 = blockIdx.x * 256 + threadIdx.x;
    float s0=0,s1=0,s2=0,s3=0,q0=0,q1=0,q2=0,q3=0,c=0;
    for (int s = tid0; s < NTILE*MAXSLOT; s += 256*256) {
        int blk = s >> 6, sl = s & 63;
        if (sl < (int)nblk[blk]) {
            float4 v = x0l[s];
            s0+=v.x; s1+=v.y; s2+=v.z; s3+=v.w;
            q0+=v.x*v.x; q1+=v.y*v.y; q2+=v.z*v.z; q3+=v.w*v.w;
            c += 1.f;
        }
    }
    float arr[9] = {s0,s1,s2,s3,q0,q1,q2,q3,c};
#pragma unroll
    for (int k=0;k<9;++k) {
        float r = waveSum(arr[k]);
        if ((threadIdx.x & 63) == 0) atomicAdd(&stats[k==8 ? 58 : k], r);
    }
}

// -------- BN1 + LeakyReLU + stride-2 conv + pool/8, scattered into x1 (32^3) --------
__global__ void k_stage1(const float4* __restrict__ x0l, const unsigned* __restrict__ list,
                         const unsigned* __restrict__ nblk, const float* __restrict__ g1,
                         const float* __restrict__ b1, const float* __restrict__ wc1,
                         const float* __restrict__ stats, float* __restrict__ x1) {
    __shared__ float wsh[256];
    __shared__ float sc[4], sh[4];
    wsh[threadIdx.x] = wc1[threadIdx.x];
    if (threadIdx.x < 4) {
        int c = threadIdx.x;
        float cnt = fmaxf(stats[58], 1.0f);
        float mean = stats[c] / cnt;
        float var  = stats[4+c] / cnt - mean*mean;
        float s = g1[c] * rsqrtf(var + BNEPS);
        sc[c] = s; sh[c] = b1[c] - mean*s;
    }
    __syncthreads();
    int s = blockIdx.x * 256 + threadIdx.x;
    int blk = s >> 6, sl = s & 63;
    if (sl >= (int)nblk[blk]) return;
    unsigned vox = list[s];
    float4 v = x0l[s];
    int w = vox & 127, h = (vox>>7)&127, d = (vox>>14)&127, b = (int)(vox>>21);
    float y[4];
    float t0 = v.x*sc[0]+sh[0]; y[0] = t0 >= 0.f ? t0 : LEAK*t0;
    float t1 = v.y*sc[1]+sh[1]; y[1] = t1 >= 0.f ? t1 : LEAK*t1;
    float t2 = v.z*sc[2]+sh[2]; y[2] = t2 >= 0.f ? t2 : LEAK*t2;
    float t3 = v.w*sc[3]+sh[3]; y[3] = t3 >= 0.f ? t3 : LEAK*t3;
    int widx = (d&1)*4 + (h&1)*2 + (w&1);
    int s32  = (d>>2)*1024 + (h>>2)*32 + (w>>2);
    float* dst = x1 + (size_t)b*8*32768 + s32;
#pragma unroll
    for (int o=0;o<8;++o) {
        const float* wp = wsh + o*32 + widx;
        float contrib = y[0]*wp[0] + y[1]*wp[8] + y[2]*wp[16] + y[3]*wp[24];
        atomicAdd(dst + o*32768, contrib * 0.125f);
    }
}

// -------- stage-2 stats: per-channel sums of x1 + mask32 count (widened) --------
__global__ void k_stage2_stats(const float4* __restrict__ x1v, const unsigned* __restrict__ mask32w,
                               float* __restrict__ stats) {
    int blk = blockIdx.x;
    if (blk < 256) {                       // 32 planes x 8 chunks of 1024 float4
        int plane = blk >> 3, chunk = blk & 7;
        const float4* p = x1v + (size_t)plane*8192 + chunk*1024;
        float s=0.f, sq=0.f;
        for (int i = threadIdx.x; i < 1024; i += 256) {
            float4 v = p[i];
            s  += v.x+v.y+v.z+v.w;
            sq += v.x*v.x+v.y*v.y+v.z*v.z+v.w*v.w;
        }
        s = waveSum(s); sq = waveSum(sq);
        if ((threadIdx.x & 63) == 0) {
            int c = plane & 7;
            atomicAdd(&stats[9 + c], s);
            atomicAdd(&stats[17 + c], sq);
        }
    } else {                               // 4 blocks: mask32 count per batch
        int b = blk - 256;
        const unsigned* m = mask32w + b*8192;
        float s = 0.f;
        for (int i = threadIdx.x; i < 8192; i += 256) {
            unsigned x = m[i];
            s += (float)((x&1u)+((x>>8)&1u)+((x>>16)&1u)+((x>>24)&1u));
        }
        s = waveSum(s);
        if ((threadIdx.x & 63) == 0) atomicAdd(&stats[8], s);
    }
}

// -------- stage 2: BN2+LReLU+mask, 2x2x2 stride2 conv (8->16), pool/8 -> x2 (8^3) --------
__global__ void k_stage2(const float* __restrict__ x1, const unsigned char* __restrict__ mask32,
                         const float* __restrict__ g2, const float* __restrict__ b2,
                         const float* __restrict__ wc2, const float* __restrict__ stats,
                         float* __restrict__ x2) {
    __shared__ float wsh[1024];
    for (int i = threadIdx.x; i < 1024; i += blockDim.x) wsh[i] = wc2[i];
    float sc[8], sh[8];
    float cnt = fmaxf(stats[8], 1.0f);
#pragma unroll
    for (int c=0;c<8;++c) {
        float mean = stats[9+c] / cnt;
        float var  = stats[17+c] / cnt - mean*mean;
        float s = g2[c] * rsqrtf(var + BNEPS);
        sc[c] = s; sh[c] = b2[c] - mean*s;
    }
    __syncthreads();
    int t = blockIdx.x * blockDim.x + threadIdx.x;  // [0, 32768) = ((b*16+o)*512)+r
    int r = t & 511, bo = t >> 9;
    int o = bo & 15, b = bo >> 4;
    int d8 = r >> 6, h8 = (r >> 3) & 7, w8 = r & 7;
    const float* xb = x1 + (size_t)b*8*32768;
    const unsigned char* mb = mask32 + b*32768;
    float acc = 0.f;
    for (int dd=0; dd<4; ++dd) for (int hh=0; hh<4; ++hh) for (int ww=0; ww<4; ++ww) {
        int s32 = ((d8*4+dd) << 10) + ((h8*4+hh) << 5) + (w8*4+ww);
        if (!mb[s32]) continue;
        int widx = (dd&1)*4 + (hh&1)*2 + (ww&1);
        const float* wp = wsh + o*64 + widx;
#pragma unroll
        for (int c=0;c<8;++c) {
            float v = xb[c*32768 + s32];
            float tt = v*sc[c] + sh[c];
            tt = (tt >= 0.f) ? tt : LEAK*tt;
            acc += tt * wp[c*8];
        }
    }
    x2[t] = acc * 0.125f;
}

// -------- stage-3 stats --------
__global__ void k_stage3_stats(const float* __restrict__ x2, const unsigned char* __restrict__ mask8,
                               float* __restrict__ stats) {
    int blk = blockIdx.x;
    if (blk < 64) {
        const float* p = x2 + (size_t)blk * 512;
        float s=0.f, sq=0.f;
        for (int i = threadIdx.x; i < 512; i += blockDim.x) { float v = p[i]; s += v; sq += v*v; }
        s = waveSum(s); sq = waveSum(sq);
        if ((threadIdx.x & 63) == 0) {
            int c = blk & 15;
            atomicAdd(&stats[26 + c], s);
            atomicAdd(&stats[42 + c], sq);
        }
    } else {
        int b = blk - 64;
        const unsigned char* m = mask8 + b*512;
        float s = 0.f;
        for (int i = threadIdx.x; i < 512; i += blockDim.x) s += (float)m[i];
        s = waveSum(s);
        if ((threadIdx.x & 63) == 0) atomicAdd(&stats[25], s);
    }
}

// -------- stage 3: BN3+LReLU+mask, conv (16->32), pool/8 -> x3 (2^3) --------
__global__ void k_stage3(const float* __restrict__ x2, const unsigned char* __restrict__ mask8,
                         const float* __restrict__ g3, const float* __restrict__ b3,
                         const float* __restrict__ wc3, const float* __restrict__ stats,
                         float* __restrict__ x3) {
    __shared__ float wsh[4096];
    for (int i = threadIdx.x; i < 4096; i += blockDim.x) wsh[i] = wc3[i];
    float sc[16], sh[16];
    float cnt = fmaxf(stats[25], 1.0f);
#pragma unroll
    for (int c=0;c<16;++c) {
        float mean = stats[26+c] / cnt;
        float var  = stats[42+c] / cnt - mean*mean;
        float s = g3[c] * rsqrtf(var + BNEPS);
        sc[c] = s; sh[c] = b3[c] - mean*s;
    }
    __syncthreads();
    int t = blockIdx.x * blockDim.x + threadIdx.x;  // [0,1024) = ((b*32+o)*8)+r
    int r = t & 7, bo = t >> 3;
    int o = bo & 31, b = bo >> 5;
    int d2 = (r >> 2) & 1, h2 = (r >> 1) & 1, w2 = r & 1;
    const float* xb = x2 + (size_t)b*16*512;
    const unsigned char* mb = mask8 + b*512;
    float acc = 0.f;
    for (int dd=0; dd<4; ++dd) for (int hh=0; hh<4; ++hh) for (int ww=0; ww<4; ++ww) {
        int s8 = (d2*4+dd)*64 + (h2*4+hh)*8 + (w2*4+ww);
        if (!mb[s8]) continue;
        int widx = (dd&1)*4 + (hh&1)*2 + (ww&1);
        const float* wp = wsh + o*128 + widx;
#pragma unroll
        for (int c=0;c<16;++c) {
            float v = xb[c*512 + s8];
            float tt = v*sc[c] + sh[c];
            tt = (tt >= 0.f) ? tt : LEAK*tt;
            acc += tt * wp[c*8];
        }
    }
    x3[t] = acc * 0.125f;
}

// -------- final linear: (4,256) @ (256,64)^T + blin --------
__global__ void k_linear(const float* __restrict__ x3, const float* __restrict__ wlin,
                         const float* __restrict__ blin, float* __restrict__ out) {
    int t = threadIdx.x;           // [0,256)
    int b = t >> 6, j = t & 63;
    float acc = blin[j];
    const float* xb = x3 + b*256;
    const float* wj = wlin + j*256;
#pragma unroll 8
    for (int k=0;k<256;++k) acc += xb[k] * wj[k];
    out[b*64 + j] = acc;
}

extern "C" void kernel_launch(void* const* d_in, const int* in_sizes, int n_in,
                              void* d_out, int out_size, void* d_ws, size_t ws_size,
                              hipStream_t stream) {
    const float* pc   = (const float*)d_in[0];
    const float* w0   = (const float*)d_in[1];
    const float* g1   = (const float*)d_in[2];
    const float* b1   = (const float*)d_in[3];
    const float* wc1  = (const float*)d_in[4];
    const float* g2   = (const float*)d_in[5];
    const float* b2   = (const float*)d_in[6];
    const float* wc2  = (const float*)d_in[7];
    const float* g3   = (const float*)d_in[8];
    const float* b3   = (const float*)d_in[9];
    const float* wc3  = (const float*)d_in[10];
    const float* wlin = (const float*)d_in[11];
    const float* blin = (const float*)d_in[12];
    float* out = (float*)d_out;

    char* ws = (char*)d_ws;
    float*         dense    = (float*)(ws + OFF_DENSE);
    unsigned*      maskbits = (unsigned*)(ws + OFF_MASKBITS);
    unsigned char* mask32   = (unsigned char*)(ws + OFF_MASK32);
    unsigned char* mask8    = (unsigned char*)(ws + OFF_MASK8);
    float*         x1       = (float*)(ws + OFF_X1);
    float*         stats    = (float*)(ws + OFF_STATS);
    unsigned*      nblk     = (unsigned*)(ws + OFF_NBLK);
    unsigned*      list     = (unsigned*)(ws + OFF_LIST);
    float4*        x0l      = (float4*)(ws + OFF_X0L);
    float*         x2       = (float*)(ws + OFF_X2);
    float*         x3       = (float*)(ws + OFF_X3);

    int n = in_sizes[0] / 5;
    int nb = (n + 255) / 256;

    (void)hipMemsetAsync(ws, 0, ZERO_BYTES, stream);
    k_scatter<<<nb, 256, 0, stream>>>(pc, dense, maskbits, mask32, mask8, n);
    k_conv0<<<dim3(16,16,64), 512, 0, stream>>>(dense, maskbits, w0, nblk, list, x0l);
    k_stats1<<<256, 256, 0, stream>>>(x0l, nblk, stats);
    k_stage1<<<NTILE*MAXSLOT/256, 256, 0, stream>>>(x0l, list, nblk, g1, b1, wc1, stats, x1);
    k_stage2_stats<<<260, 256, 0, stream>>>((const float4*)x1, (const unsigned*)mask32, stats);
    k_stage2<<<128, 256, 0, stream>>>(x1, mask32, g2, b2, wc2, stats, x2);
    k_stage3_stats<<<68, 256, 0, stream>>>(x2, mask8, stats);
    k_stage3<<<4, 256, 0, stream>>>(x2, mask8, g3, b3, wc3, stats, x3);
    k_linear<<<1, 256, 0, stream>>>(x3, wlin, blin, out);
}

// Round 7
// 341.961 us; speedup vs baseline: 1.9307x; 1.2521x over previous
//
#include <hip/hip_runtime.h>

#define SS 128
#define S3 (SS*SS*SS)
#define NBATCH 4
#define LEAK 0.01f
#define BNEPS 1e-4f
#define NTILE 16384          // 4 batches * 16^3 tiles of 8^3
#define MAXSLOT 64

// ---------------- workspace layout (bytes) ----------------
// zeroed each launch:
constexpr size_t OFF_DENSE    = 0;                                   // f32 [4][128^3]   33.5MB
constexpr size_t OFF_MASKBITS = OFF_DENSE + (size_t)NBATCH*S3*4;     // u32 bitgrid       1MB
constexpr size_t OFF_X1       = OFF_MASKBITS + (size_t)NBATCH*S3/8;  // f32 [4][8][32^3]  4MB (atomic acc)
constexpr size_t ZERO_BYTES   = OFF_X1 + (size_t)NBATCH*8*32768*4;
// fully overwritten each launch (no zeroing needed):
constexpr size_t OFF_MASK32   = ZERO_BYTES;                          // u8 [4][32^3] (written by conv0)
constexpr size_t OFF_MASK8    = OFF_MASK32 + (size_t)NBATCH*32768;   // u8 [4][8^3]  (written by prep1)
constexpr size_t OFF_STATS    = OFF_MASK8 + (size_t)NBATCH*512;      // f32 [64] coefs (written by preps)
constexpr size_t OFF_P1       = OFF_STATS + 256;                     // f32 [256][9]
constexpr size_t OFF_P2       = OFF_P1 + 256*9*4;                    // f32 [256][2]
constexpr size_t OFF_P3       = OFF_P2 + 256*2*4;                    // f32 [64][2]
constexpr size_t OFF_NBLK     = OFF_P3 + 64*2*4;                     // u32 [16384]
constexpr size_t OFF_LIST     = OFF_NBLK + NTILE*4;                  // u32 [16384][64]
constexpr size_t OFF_X0L      = OFF_LIST + (size_t)NTILE*MAXSLOT*4;  // f32x4 [16384][64]
constexpr size_t OFF_X2       = OFF_X0L + (size_t)NTILE*MAXSLOT*16;  // f32 [4][16][8^3]
constexpr size_t OFF_X3       = OFF_X2 + (size_t)NBATCH*16*512*4;    // f32 [4][32][2^3]

// stats float slots: [0]=cnt2 [1]=cnt8 [2..5]=sc1 [6..9]=sh1 [10..17]=sc2 [18..25]=sh2
//                    [26..41]=sc3 [42..57]=sh3

__device__ inline float waveSum(float v) {
#pragma unroll
    for (int off = 32; off; off >>= 1) v += __shfl_xor(v, off, 64);
    return v;
}

// -------- scatter points; dedup via bit grid --------
__global__ void k_scatter(const float* __restrict__ pc, float* __restrict__ dense,
                          unsigned* __restrict__ maskbits, int n) {
    int i = blockIdx.x * blockDim.x + threadIdx.x;
    if (i >= n) return;
    float c0 = pc[i*5+0], c1 = pc[i*5+1], c2 = pc[i*5+2], cb = pc[i*5+3], f = pc[i*5+4];
    int d = (int)c0, h = (int)c1, w = (int)c2, b = (int)cb;
    unsigned vox = (((unsigned)b*SS + d)*SS + h)*SS + w;
    atomicAdd(&dense[vox], f);
    atomicOr(&maskbits[vox >> 5], 1u << (vox & 31));
}

// -------- dense tiled conv0 (3x3x3 SAME) + compaction + mask32 --------
__global__ __launch_bounds__(512) void k_conv0(const float* __restrict__ dense,
                                               const unsigned* __restrict__ maskbits,
                                               const float* __restrict__ w0g,
                                               unsigned* __restrict__ nblk,
                                               unsigned* __restrict__ list,
                                               float4* __restrict__ x0l,
                                               unsigned char* __restrict__ mask32) {
    __shared__ float tile[1000];   // 10x10x10 halo tile
    __shared__ float ws[108];
    __shared__ unsigned wtot[8];
    __shared__ unsigned char cellocc[8];
    int tid = threadIdx.x;
    int tw = blockIdx.x, th = blockIdx.y, tzb = blockIdx.z;   // tzb = b*16 + d-tile
    int b = tzb >> 4, td = tzb & 15;
    int d0 = td*8, h0 = th*8, wo = tw*8;
    if (tid < 108) ws[tid] = w0g[tid];
    if (tid >= 112 && tid < 120) cellocc[tid-112] = 0;
    const float* dn = dense + (size_t)b * S3;
    for (int i = tid; i < 1000; i += 512) {
        int dz = i/100, rem = i - dz*100, dy = rem/10, dx = rem - dy*10;
        int gz = d0-1+dz, gy = h0-1+dy, gx = wo-1+dx;
        float v = 0.f;
        if ((unsigned)gz < SS && (unsigned)gy < SS && (unsigned)gx < SS)
            v = dn[((size_t)gz*SS + gy)*SS + gx];
        tile[i] = v;
    }
    __syncthreads();
    int tz = tid >> 6, ty = (tid >> 3) & 7, tx = tid & 7;
    int gz = d0+tz, gy = h0+ty, gx = wo+tx;
    unsigned vox = (((unsigned)b*SS + gz)*SS + gy)*SS + gx;
    bool occ = (maskbits[vox >> 5] >> (vox & 31)) & 1u;
    float a0=0.f, a1=0.f, a2=0.f, a3=0.f;
    if (occ) {
        cellocc[((tz>>2)<<2) | ((ty>>2)<<1) | (tx>>2)] = 1;
#pragma unroll
        for (int kd=0; kd<3; ++kd)
#pragma unroll
            for (int kh=0; kh<3; ++kh)
#pragma unroll
                for (int kw=0; kw<3; ++kw) {
                    float v = tile[(tz+kd)*100 + (ty+kh)*10 + (tx+kw)];
                    int kk = kd*9 + kh*3 + kw;
                    a0 += v*ws[kk]; a1 += v*ws[27+kk]; a2 += v*ws[54+kk]; a3 += v*ws[81+kk];
                }
    }
    unsigned long long ball = __ballot(occ);
    int lane = tid & 63, wid = tid >> 6;
    if (lane == 0) wtot[wid] = __popcll(ball);
    __syncthreads();
    unsigned base = 0, total = 0;
#pragma unroll
    for (int j=0;j<8;++j) { unsigned t = wtot[j]; if (j < wid) base += t; total += t; }
    int blk = (tzb*16 + th)*16 + tw;
    if (tid == 0) nblk[blk] = total < MAXSLOT ? total : MAXSLOT;
    if (tid < 8) {
        int cz = (tid>>2)&1, cy = (tid>>1)&1, cx = tid&1;
        mask32[b*32768 + ((d0>>2)+cz)*1024 + ((h0>>2)+cy)*32 + ((wo>>2)+cx)] = cellocc[tid];
    }
    if (occ) {
        unsigned pos = base + __popcll(ball & ((1ull << lane) - 1ull));
        if (pos < MAXSLOT) {
            list[(size_t)blk*MAXSLOT + pos] = vox;
            x0l[(size_t)blk*MAXSLOT + pos] = make_float4(a0, a1, a2, a3);
        }
    }
}

// -------- BN1 statistics partials (no global atomics) --------
__global__ void k_stats1(const float4* __restrict__ x0l, const unsigned* __restrict__ nblk,
                         float* __restrict__ p1) {
    __shared__ float red[4][9];
    int tid = threadIdx.x;
    int tid0 = blockIdx.x * 256 + tid;
    float a[9] = {0,0,0,0,0,0,0,0,0};
    for (int s = tid0; s < NTILE*MAXSLOT; s += 65536) {
        int blk = s >> 6, sl = s & 63;
        if (sl < (int)nblk[blk]) {
            float4 v = x0l[s];
            a[0]+=v.x; a[1]+=v.y; a[2]+=v.z; a[3]+=v.w;
            a[4]+=v.x*v.x; a[5]+=v.y*v.y; a[6]+=v.z*v.z; a[7]+=v.w*v.w;
            a[8]+=1.f;
        }
    }
#pragma unroll
    for (int k=0;k<9;++k) a[k] = waveSum(a[k]);
    int wid = tid>>6, lane = tid&63;
    if (lane < 9) red[wid][lane] = a[lane];
    __syncthreads();
    if (tid < 9) p1[blockIdx.x*9+tid] = red[0][tid]+red[1][tid]+red[2][tid]+red[3][tid];
}

// -------- final reduce for BN1 + mask8 + cnt2/cnt8 --------
__global__ __launch_bounds__(256) void k_prep1(const float* __restrict__ p1,
        const unsigned char* __restrict__ mask32, unsigned char* __restrict__ mask8,
        const float* __restrict__ g1, const float* __restrict__ b1, float* __restrict__ stats) {
    __shared__ float red[4][9];
    __shared__ float tot[9];
    __shared__ float redc[8];
    int tid = threadIdx.x;
    int wid = tid>>6, lane = tid&63;
    float a[9];
#pragma unroll
    for (int k=0;k<9;++k) a[k] = p1[tid*9+k];
#pragma unroll
    for (int k=0;k<9;++k) a[k] = waveSum(a[k]);
    if (lane < 9) red[wid][lane] = a[lane];
    __syncthreads();
    if (tid < 9) tot[tid] = red[0][tid]+red[1][tid]+red[2][tid]+red[3][tid];
    __syncthreads();
    if (tid < 4) {
        float cnt = fmaxf(tot[8], 1.f);
        float mean = tot[tid] / cnt;
        float var  = tot[4+tid] / cnt - mean*mean;
        float s = g1[tid] * rsqrtf(var + BNEPS);
        stats[2+tid] = s; stats[6+tid] = b1[tid] - mean*s;
    }
    // mask8 derivation + cnt8
    float c8 = 0.f;
    for (int i = tid; i < NBATCH*512; i += 256) {
        int b = i>>9, r = i&511;
        int d8 = r>>6, h8 = (r>>3)&7, w8 = r&7;
        const unsigned char* m = mask32 + b*32768;
        unsigned v = 0;
#pragma unroll
        for (int dz=0;dz<2;++dz)
#pragma unroll
            for (int dy=0;dy<2;++dy)
#pragma unroll
                for (int dx=0;dx<2;++dx)
                    v |= m[(2*d8+dz)*1024 + (2*h8+dy)*32 + (2*w8+dx)];
        mask8[i] = (unsigned char)v;
        c8 += (float)v;
    }
    // cnt2 = sum(mask32)
    const unsigned* mw = (const unsigned*)mask32;
    float c2 = 0.f;
    for (int i = tid; i < NBATCH*8192; i += 256) {
        unsigned x = mw[i];
        c2 += (float)((x&1u)+((x>>8)&1u)+((x>>16)&1u)+((x>>24)&1u));
    }
    c8 = waveSum(c8); c2 = waveSum(c2);
    if (lane == 0) { redc[wid] = c2; redc[4+wid] = c8; }
    __syncthreads();
    if (tid == 0) stats[0] = redc[0]+redc[1]+redc[2]+redc[3];
    if (tid == 1) stats[1] = redc[4]+redc[5]+redc[6]+redc[7];
}

// -------- BN1 + LeakyReLU + stride-2 conv + pool/8, scattered into x1 (32^3) --------
__global__ void k_stage1(const float4* __restrict__ x0l, const unsigned* __restrict__ list,
                         const unsigned* __restrict__ nblk, const float* __restrict__ wc1,
                         const float* __restrict__ stats, float* __restrict__ x1) {
    __shared__ float wsh[256];
    __shared__ float sc[4], sh[4];
    wsh[threadIdx.x] = wc1[threadIdx.x];
    if (threadIdx.x < 4) { sc[threadIdx.x] = stats[2+threadIdx.x]; sh[threadIdx.x] = stats[6+threadIdx.x]; }
    __syncthreads();
    int s = blockIdx.x * 256 + threadIdx.x;
    int blk = s >> 6, sl = s & 63;
    if (sl >= (int)nblk[blk]) return;
    unsigned vox = list[s];
    float4 v = x0l[s];
    int w = vox & 127, h = (vox>>7)&127, d = (vox>>14)&127, b = (int)(vox>>21);
    float y[4];
    float t0 = v.x*sc[0]+sh[0]; y[0] = t0 >= 0.f ? t0 : LEAK*t0;
    float t1 = v.y*sc[1]+sh[1]; y[1] = t1 >= 0.f ? t1 : LEAK*t1;
    float t2 = v.z*sc[2]+sh[2]; y[2] = t2 >= 0.f ? t2 : LEAK*t2;
    float t3 = v.w*sc[3]+sh[3]; y[3] = t3 >= 0.f ? t3 : LEAK*t3;
    int widx = (d&1)*4 + (h&1)*2 + (w&1);
    int s32  = (d>>2)*1024 + (h>>2)*32 + (w>>2);
    float* dst = x1 + (size_t)b*8*32768 + s32;
#pragma unroll
    for (int o=0;o<8;++o) {
        const float* wp = wsh + o*32 + widx;
        float contrib = y[0]*wp[0] + y[1]*wp[8] + y[2]*wp[16] + y[3]*wp[24];
        atomicAdd(dst + o*32768, contrib * 0.125f);
    }
}

// -------- stage-2 stats partials --------
__global__ void k_s2stats(const float4* __restrict__ x1v, float* __restrict__ p2) {
    __shared__ float red[4][2];
    int blk = blockIdx.x;              // 256 = plane(32) x chunk(8)
    int plane = blk >> 3, chunk = blk & 7;
    const float4* p = x1v + (size_t)plane*8192 + chunk*1024;
    float s=0.f, sq=0.f;
    for (int i = threadIdx.x; i < 1024; i += 256) {
        float4 v = p[i];
        s  += v.x+v.y+v.z+v.w;
        sq += v.x*v.x+v.y*v.y+v.z*v.z+v.w*v.w;
    }
    s = waveSum(s); sq = waveSum(sq);
    int wid = threadIdx.x>>6, lane = threadIdx.x&63;
    if (lane == 0) { red[wid][0] = s; red[wid][1] = sq; }
    __syncthreads();
    if (threadIdx.x < 2)
        p2[blk*2+threadIdx.x] = red[0][threadIdx.x]+red[1][threadIdx.x]+red[2][threadIdx.x]+red[3][threadIdx.x];
}

__global__ void k_prep2(const float* __restrict__ p2, const float* __restrict__ g2,
                        const float* __restrict__ b2, float* __restrict__ stats) {
    __shared__ float sm[16];
    int tid = threadIdx.x;
    if (tid < 16) {
        int c = tid & 7, q = tid >> 3;
        float s = 0.f;
        for (int b=0;b<4;++b)
            for (int ch=0;ch<8;++ch)
                s += p2[((b*8+c)*8+ch)*2 + q];
        sm[tid] = s;
    }
    __syncthreads();
    if (tid < 8) {
        float cnt = fmaxf(stats[0], 1.f);
        float mean = sm[tid] / cnt;
        float var  = sm[8+tid] / cnt - mean*mean;
        float s = g2[tid] * rsqrtf(var + BNEPS);
        stats[10+tid] = s; stats[18+tid] = b2[tid] - mean*s;
    }
}

// -------- stage 2: BN2+LReLU+mask, conv (8->16), pool/8 -> x2 (8^3) --------
__global__ void k_stage2(const float* __restrict__ x1, const unsigned char* __restrict__ mask32,
                         const float* __restrict__ wc2, const float* __restrict__ stats,
                         float* __restrict__ x2) {
    __shared__ float wsh[1024];
    __shared__ float scs[8], shs[8];
    for (int i = threadIdx.x; i < 1024; i += blockDim.x) wsh[i] = wc2[i];
    if (threadIdx.x < 8) { scs[threadIdx.x] = stats[10+threadIdx.x]; shs[threadIdx.x] = stats[18+threadIdx.x]; }
    __syncthreads();
    int t = blockIdx.x * blockDim.x + threadIdx.x;  // [0, 32768) = ((b*16+o)*512)+r
    int r = t & 511, bo = t >> 9;
    int o = bo & 15, b = bo >> 4;
    int d8 = r >> 6, h8 = (r >> 3) & 7, w8 = r & 7;
    const float* xb = x1 + (size_t)b*8*32768;
    const unsigned char* mb = mask32 + b*32768;
    float acc = 0.f;
    for (int dd=0; dd<4; ++dd) for (int hh=0; hh<4; ++hh) for (int ww=0; ww<4; ++ww) {
        int s32 = ((d8*4+dd) << 10) + ((h8*4+hh) << 5) + (w8*4+ww);
        if (!mb[s32]) continue;
        int widx = (dd&1)*4 + (hh&1)*2 + (ww&1);
        const float* wp = wsh + o*64 + widx;
#pragma unroll
        for (int c=0;c<8;++c) {
            float v = xb[c*32768 + s32];
            float tt = v*scs[c] + shs[c];
            tt = (tt >= 0.f) ? tt : LEAK*tt;
            acc += tt * wp[c*8];
        }
    }
    x2[t] = acc * 0.125f;
}

// -------- stage-3 stats partials --------
__global__ void k_s3stats(const float* __restrict__ x2, float* __restrict__ p3) {
    __shared__ float red[4][2];
    const float* p = x2 + (size_t)blockIdx.x * 512;   // 64 planes
    float s=0.f, sq=0.f;
    for (int i = threadIdx.x; i < 512; i += 256) { float v = p[i]; s += v; sq += v*v; }
    s = waveSum(s); sq = waveSum(sq);
    int wid = threadIdx.x>>6, lane = threadIdx.x&63;
    if (lane == 0) { red[wid][0] = s; red[wid][1] = sq; }
    __syncthreads();
    if (threadIdx.x < 2)
        p3[blockIdx.x*2+threadIdx.x] = red[0][threadIdx.x]+red[1][threadIdx.x]+red[2][threadIdx.x]+red[3][threadIdx.x];
}

__global__ void k_prep3(const float* __restrict__ p3, const float* __restrict__ g3,
                        const float* __restrict__ b3, float* __restrict__ stats) {
    __shared__ float sm[32];
    int tid = threadIdx.x;
    if (tid < 32) {
        int c = tid & 15, q = tid >> 4;
        float s = 0.f;
        for (int b=0;b<4;++b) s += p3[(b*16+c)*2 + q];
        sm[tid] = s;
    }
    __syncthreads();
    if (tid < 16) {
        float cnt = fmaxf(stats[1], 1.f);
        float mean = sm[tid] / cnt;
        float var  = sm[16+tid] / cnt - mean*mean;
        float s = g3[tid] * rsqrtf(var + BNEPS);
        stats[26+tid] = s; stats[42+tid] = b3[tid] - mean*s;
    }
}

// -------- stage 3: BN3+LReLU+mask, conv (16->32), pool/8 -> x3 (2^3) --------
__global__ void k_stage3(const float* __restrict__ x2, const unsigned char* __restrict__ mask8,
                         const float* __restrict__ wc3, const float* __restrict__ stats,
                         float* __restrict__ x3) {
    __shared__ float wsh[4096];
    __shared__ float scs[16], shs[16];
    for (int i = threadIdx.x; i < 4096; i += blockDim.x) wsh[i] = wc3[i];
    if (threadIdx.x < 16) { scs[threadIdx.x] = stats[26+threadIdx.x]; shs[threadIdx.x] = stats[42+threadIdx.x]; }
    __syncthreads();
    int t = blockIdx.x * blockDim.x + threadIdx.x;  // [0,1024) = ((b*32+o)*8)+r
    int r = t & 7, bo = t >> 3;
    int o = bo & 31, b = bo >> 5;
    int d2 = (r >> 2) & 1, h2 = (r >> 1) & 1, w2 = r & 1;
    const float* xb = x2 + (size_t)b*16*512;
    const unsigned char* mb = mask8 + b*512;
    float acc = 0.f;
    for (int dd=0; dd<4; ++dd) for (int hh=0; hh<4; ++hh) for (int ww=0; ww<4; ++ww) {
        int s8 = (d2*4+dd)*64 + (h2*4+hh)*8 + (w2*4+ww);
        if (!mb[s8]) continue;
        int widx = (dd&1)*4 + (hh&1)*2 + (ww&1);
        const float* wp = wsh + o*128 + widx;
#pragma unroll
        for (int c=0;c<16;++c) {
            float v = xb[c*512 + s8];
            float tt = v*scs[c] + shs[c];
            tt = (tt >= 0.f) ? tt : LEAK*tt;
            acc += tt * wp[c*8];
        }
    }
    x3[t] = acc * 0.125f;
}

// -------- final linear: (4,256) @ (256,64)^T + blin --------
__global__ void k_linear(const float* __restrict__ x3, const float* __restrict__ wlin,
                         const float* __restrict__ blin, float* __restrict__ out) {
    int t = threadIdx.x;           // [0,256)
    int b = t >> 6, j = t & 63;
    float acc = blin[j];
    const float* xb = x3 + b*256;
    const float* wj = wlin + j*256;
#pragma unroll 8
    for (int k=0;k<256;++k) acc += xb[k] * wj[k];
    out[b*64 + j] = acc;
}

extern "C" void kernel_launch(void* const* d_in, const int* in_sizes, int n_in,
                              void* d_out, int out_size, void* d_ws, size_t ws_size,
                              hipStream_t stream) {
    const float* pc   = (const float*)d_in[0];
    const float* w0   = (const float*)d_in[1];
    const float* g1   = (const float*)d_in[2];
    const float* b1   = (const float*)d_in[3];
    const float* wc1  = (const float*)d_in[4];
    const float* g2   = (const float*)d_in[5];
    const float* b2   = (const float*)d_in[6];
    const float* wc2  = (const float*)d_in[7];
    const float* g3   = (const float*)d_in[8];
    const float* b3   = (const float*)d_in[9];
    const float* wc3  = (const float*)d_in[10];
    const float* wlin = (const float*)d_in[11];
    const float* blin = (const float*)d_in[12];
    float* out = (float*)d_out;

    char* ws = (char*)d_ws;
    float*         dense    = (float*)(ws + OFF_DENSE);
    unsigned*      maskbits = (unsigned*)(ws + OFF_MASKBITS);
    float*         x1       = (float*)(ws + OFF_X1);
    unsigned char* mask32   = (unsigned char*)(ws + OFF_MASK32);
    unsigned char* mask8    = (unsigned char*)(ws + OFF_MASK8);
    float*         stats    = (float*)(ws + OFF_STATS);
    float*         p1       = (float*)(ws + OFF_P1);
    float*         p2       = (float*)(ws + OFF_P2);
    float*         p3       = (float*)(ws + OFF_P3);
    unsigned*      nblk     = (unsigned*)(ws + OFF_NBLK);
    unsigned*      list     = (unsigned*)(ws + OFF_LIST);
    float4*        x0l      = (float4*)(ws + OFF_X0L);
    float*         x2       = (float*)(ws + OFF_X2);
    float*         x3       = (float*)(ws + OFF_X3);

    int n = in_sizes[0] / 5;
    int nb = (n + 255) / 256;

    (void)hipMemsetAsync(ws, 0, ZERO_BYTES, stream);
    k_scatter<<<nb, 256, 0, stream>>>(pc, dense, maskbits, n);
    k_conv0<<<dim3(16,16,64), 512, 0, stream>>>(dense, maskbits, w0, nblk, list, x0l, mask32);
    k_stats1<<<256, 256, 0, stream>>>(x0l, nblk, p1);
    k_prep1<<<1, 256, 0, stream>>>(p1, mask32, mask8, g1, b1, stats);
    k_stage1<<<NTILE*MAXSLOT/256, 256, 0, stream>>>(x0l, list, nblk, wc1, stats, x1);
    k_s2stats<<<256, 256, 0, stream>>>((const float4*)x1, p2);
    k_prep2<<<1, 64, 0, stream>>>(p2, g2, b2, stats);
    k_stage2<<<128, 256, 0, stream>>>(x1, mask32, wc2, stats, x2);
    k_s3stats<<<64, 256, 0, stream>>>(x2, p3);
    k_prep3<<<1, 64, 0, stream>>>(p3, g3, b3, stats);
    k_stage3<<<4, 256, 0, stream>>>(x2, mask8, wc3, stats, x3);
    k_linear<<<1, 256, 0, stream>>>(x3, wlin, blin, out);
}

// Round 8
// 235.287 us; speedup vs baseline: 2.8061x; 1.4534x over previous
//
#include <hip/hip_runtime.h>

#define SS 128
#define S3 (SS*SS*SS)
#define NBATCH 4
#define LEAK 0.01f
#define BNEPS 1e-4f
#define NTILE 16384          // 4 batches * 16^3 tiles of 8^3
#define MAXSLOT 64

// ---------------- workspace layout (bytes) ----------------
// zeroed each launch:
constexpr size_t OFF_DENSE    = 0;                                   // f32 [4][128^3]   33.5MB
constexpr size_t OFF_MASKBITS = OFF_DENSE + (size_t)NBATCH*S3*4;     // u32 bitgrid       1MB
constexpr size_t OFF_X1       = OFF_MASKBITS + (size_t)NBATCH*S3/8;  // f32 [4][8][32^3]  4MB (atomic acc)
constexpr size_t ZERO_BYTES   = OFF_X1 + (size_t)NBATCH*8*32768*4;
// fully overwritten each launch (no zeroing needed):
constexpr size_t OFF_MASK32   = ZERO_BYTES;                          // u8 [4][32^3] (written by conv0)
constexpr size_t OFF_MASK8    = OFF_MASK32 + (size_t)NBATCH*32768;   // u8 [4][8^3]  (written by prep1)
constexpr size_t OFF_STATS    = OFF_MASK8 + (size_t)NBATCH*512;      // f32 [64] coefs (written by preps)
constexpr size_t OFF_P1       = OFF_STATS + 256;                     // f32 [256][9]
constexpr size_t OFF_P2       = OFF_P1 + 256*9*4;                    // f32 [256][2]
constexpr size_t OFF_P3       = OFF_P2 + 256*2*4;                    // f32 [64][2]
constexpr size_t OFF_NBLK     = OFF_P3 + 64*2*4;                     // u32 [16384]
constexpr size_t OFF_LIST     = OFF_NBLK + NTILE*4;                  // u32 [16384][64]
constexpr size_t OFF_X0L      = OFF_LIST + (size_t)NTILE*MAXSLOT*4;  // f32x4 [16384][64]
constexpr size_t OFF_X2       = OFF_X0L + (size_t)NTILE*MAXSLOT*16;  // f32 [4][16][8^3]
constexpr size_t OFF_X3       = OFF_X2 + (size_t)NBATCH*16*512*4;    // f32 [4][32][2^3]

// stats float slots: [0]=cnt2 [1]=cnt8 [2..5]=sc1 [6..9]=sh1 [10..17]=sc2 [18..25]=sh2
//                    [26..41]=sc3 [42..57]=sh3

__device__ inline float waveSum(float v) {
#pragma unroll
    for (int off = 32; off; off >>= 1) v += __shfl_xor(v, off, 64);
    return v;
}

// -------- scatter points; dedup via bit grid --------
__global__ void k_scatter(const float* __restrict__ pc, float* __restrict__ dense,
                          unsigned* __restrict__ maskbits, int n) {
    int i = blockIdx.x * blockDim.x + threadIdx.x;
    if (i >= n) return;
    float c0 = pc[i*5+0], c1 = pc[i*5+1], c2 = pc[i*5+2], cb = pc[i*5+3], f = pc[i*5+4];
    int d = (int)c0, h = (int)c1, w = (int)c2, b = (int)cb;
    unsigned vox = (((unsigned)b*SS + d)*SS + h)*SS + w;
    atomicAdd(&dense[vox], f);
    atomicOr(&maskbits[vox >> 5], 1u << (vox & 31));
}

// -------- dense tiled conv0 (3x3x3 SAME) + compaction + mask32 --------
__global__ __launch_bounds__(512) void k_conv0(const float* __restrict__ dense,
                                               const unsigned* __restrict__ maskbits,
                                               const float* __restrict__ w0g,
                                               unsigned* __restrict__ nblk,
                                               unsigned* __restrict__ list,
                                               float4* __restrict__ x0l,
                                               unsigned char* __restrict__ mask32) {
    __shared__ float tile[1000];   // 10x10x10 halo tile
    __shared__ float ws[108];
    __shared__ unsigned wtot[8];
    __shared__ unsigned char cellocc[8];
    int tid = threadIdx.x;
    int tw = blockIdx.x, th = blockIdx.y, tzb = blockIdx.z;   // tzb = b*16 + d-tile
    int b = tzb >> 4, td = tzb & 15;
    int d0 = td*8, h0 = th*8, wo = tw*8;
    if (tid < 108) ws[tid] = w0g[tid];
    if (tid >= 112 && tid < 120) cellocc[tid-112] = 0;
    const float* dn = dense + (size_t)b * S3;
    for (int i = tid; i < 1000; i += 512) {
        int dz = i/100, rem = i - dz*100, dy = rem/10, dx = rem - dy*10;
        int gz = d0-1+dz, gy = h0-1+dy, gx = wo-1+dx;
        float v = 0.f;
        if ((unsigned)gz < SS && (unsigned)gy < SS && (unsigned)gx < SS)
            v = dn[((size_t)gz*SS + gy)*SS + gx];
        tile[i] = v;
    }
    __syncthreads();
    int tz = tid >> 6, ty = (tid >> 3) & 7, tx = tid & 7;
    int gz = d0+tz, gy = h0+ty, gx = wo+tx;
    unsigned vox = (((unsigned)b*SS + gz)*SS + gy)*SS + gx;
    bool occ = (maskbits[vox >> 5] >> (vox & 31)) & 1u;
    float a0=0.f, a1=0.f, a2=0.f, a3=0.f;
    if (occ) {
        cellocc[((tz>>2)<<2) | ((ty>>2)<<1) | (tx>>2)] = 1;
#pragma unroll
        for (int kd=0; kd<3; ++kd)
#pragma unroll
            for (int kh=0; kh<3; ++kh)
#pragma unroll
                for (int kw=0; kw<3; ++kw) {
                    float v = tile[(tz+kd)*100 + (ty+kh)*10 + (tx+kw)];
                    int kk = kd*9 + kh*3 + kw;
                    a0 += v*ws[kk]; a1 += v*ws[27+kk]; a2 += v*ws[54+kk]; a3 += v*ws[81+kk];
                }
    }
    unsigned long long ball = __ballot(occ);
    int lane = tid & 63, wid = tid >> 6;
    if (lane == 0) wtot[wid] = __popcll(ball);
    __syncthreads();
    unsigned base = 0, total = 0;
#pragma unroll
    for (int j=0;j<8;++j) { unsigned t = wtot[j]; if (j < wid) base += t; total += t; }
    int blk = (tzb*16 + th)*16 + tw;
    if (tid == 0) nblk[blk] = total < MAXSLOT ? total : MAXSLOT;
    if (tid < 8) {
        int cz = (tid>>2)&1, cy = (tid>>1)&1, cx = tid&1;
        mask32[b*32768 + ((d0>>2)+cz)*1024 + ((h0>>2)+cy)*32 + ((wo>>2)+cx)] = cellocc[tid];
    }
    if (occ) {
        unsigned pos = base + __popcll(ball & ((1ull << lane) - 1ull));
        if (pos < MAXSLOT) {
            list[(size_t)blk*MAXSLOT + pos] = vox;
            x0l[(size_t)blk*MAXSLOT + pos] = make_float4(a0, a1, a2, a3);
        }
    }
}

// -------- BN1 statistics partials (no global atomics) --------
__global__ void k_stats1(const float4* __restrict__ x0l, const unsigned* __restrict__ nblk,
                         float* __restrict__ p1) {
    __shared__ float red[4][9];
    int tid = threadIdx.x;
    int tid0 = blockIdx.x * 256 + tid;
    float a[9] = {0,0,0,0,0,0,0,0,0};
    for (int s = tid0; s < NTILE*MAXSLOT; s += 65536) {
        int blk = s >> 6, sl = s & 63;
        if (sl < (int)nblk[blk]) {
            float4 v = x0l[s];
            a[0]+=v.x; a[1]+=v.y; a[2]+=v.z; a[3]+=v.w;
            a[4]+=v.x*v.x; a[5]+=v.y*v.y; a[6]+=v.z*v.z; a[7]+=v.w*v.w;
            a[8]+=1.f;
        }
    }
#pragma unroll
    for (int k=0;k<9;++k) a[k] = waveSum(a[k]);
    int wid = tid>>6, lane = tid&63;
    if (lane < 9) red[wid][lane] = a[lane];
    __syncthreads();
    if (tid < 9) p1[blockIdx.x*9+tid] = red[0][tid]+red[1][tid]+red[2][tid]+red[3][tid];
}

// -------- final reduce for BN1 + mask8 + cnt2/cnt8 --------
__global__ __launch_bounds__(256) void k_prep1(const float* __restrict__ p1,
        const unsigned char* __restrict__ mask32, unsigned char* __restrict__ mask8,
        const float* __restrict__ g1, const float* __restrict__ b1, float* __restrict__ stats) {
    __shared__ float red[4][9];
    __shared__ float tot[9];
    __shared__ float redc[8];
    int tid = threadIdx.x;
    int wid = tid>>6, lane = tid&63;
    float a[9];
#pragma unroll
    for (int k=0;k<9;++k) a[k] = p1[tid*9+k];
#pragma unroll
    for (int k=0;k<9;++k) a[k] = waveSum(a[k]);
    if (lane < 9) red[wid][lane] = a[lane];
    __syncthreads();
    if (tid < 9) tot[tid] = red[0][tid]+red[1][tid]+red[2][tid]+red[3][tid];
    __syncthreads();
    if (tid < 4) {
        float cnt = fmaxf(tot[8], 1.f);
        float mean = tot[tid] / cnt;
        float var  = tot[4+tid] / cnt - mean*mean;
        float s = g1[tid] * rsqrtf(var + BNEPS);
        stats[2+tid] = s; stats[6+tid] = b1[tid] - mean*s;
    }
    // mask8 derivation + cnt8
    float c8 = 0.f;
    for (int i = tid; i < NBATCH*512; i += 256) {
        int b = i>>9, r = i&511;
        int d8 = r>>6, h8 = (r>>3)&7, w8 = r&7;
        const unsigned char* m = mask32 + b*32768;
        unsigned v = 0;
#pragma unroll
        for (int dz=0;dz<2;++dz)
#pragma unroll
            for (int dy=0;dy<2;++dy)
#pragma unroll
                for (int dx=0;dx<2;++dx)
                    v |= m[(2*d8+dz)*1024 + (2*h8+dy)*32 + (2*w8+dx)];
        mask8[i] = (unsigned char)v;
        c8 += (float)v;
    }
    // cnt2 = sum(mask32)
    const unsigned* mw = (const unsigned*)mask32;
    float c2 = 0.f;
    for (int i = tid; i < NBATCH*8192; i += 256) {
        unsigned x = mw[i];
        c2 += (float)((x&1u)+((x>>8)&1u)+((x>>16)&1u)+((x>>24)&1u));
    }
    c8 = waveSum(c8); c2 = waveSum(c2);
    if (lane == 0) { redc[wid] = c2; redc[4+wid] = c8; }
    __syncthreads();
    if (tid == 0) stats[0] = redc[0]+redc[1]+redc[2]+redc[3];
    if (tid == 1) stats[1] = redc[4]+redc[5]+redc[6]+redc[7];
}

// -------- BN1 + LeakyReLU + stride-2 conv + pool/8, scattered into x1 (32^3) --------
__global__ void k_stage1(const float4* __restrict__ x0l, const unsigned* __restrict__ list,
                         const unsigned* __restrict__ nblk, const float* __restrict__ wc1,
                         const float* __restrict__ stats, float* __restrict__ x1) {
    __shared__ float wsh[256];
    __shared__ float sc[4], sh[4];
    wsh[threadIdx.x] = wc1[threadIdx.x];
    if (threadIdx.x < 4) { sc[threadIdx.x] = stats[2+threadIdx.x]; sh[threadIdx.x] = stats[6+threadIdx.x]; }
    __syncthreads();
    int s = blockIdx.x * 256 + threadIdx.x;
    int blk = s >> 6, sl = s & 63;
    if (sl >= (int)nblk[blk]) return;
    unsigned vox = list[s];
    float4 v = x0l[s];
    int w = vox & 127, h = (vox>>7)&127, d = (vox>>14)&127, b = (int)(vox>>21);
    float y[4];
    float t0 = v.x*sc[0]+sh[0]; y[0] = t0 >= 0.f ? t0 : LEAK*t0;
    float t1 = v.y*sc[1]+sh[1]; y[1] = t1 >= 0.f ? t1 : LEAK*t1;
    float t2 = v.z*sc[2]+sh[2]; y[2] = t2 >= 0.f ? t2 : LEAK*t2;
    float t3 = v.w*sc[3]+sh[3]; y[3] = t3 >= 0.f ? t3 : LEAK*t3;
    int widx = (d&1)*4 + (h&1)*2 + (w&1);
    int s32  = (d>>2)*1024 + (h>>2)*32 + (w>>2);
    float* dst = x1 + (size_t)b*8*32768 + s32;
#pragma unroll
    for (int o=0;o<8;++o) {
        const float* wp = wsh + o*32 + widx;
        float contrib = y[0]*wp[0] + y[1]*wp[8] + y[2]*wp[16] + y[3]*wp[24];
        atomicAdd(dst + o*32768, contrib * 0.125f);
    }
}

// -------- stage-2 stats partials --------
__global__ void k_s2stats(const float4* __restrict__ x1v, float* __restrict__ p2) {
    __shared__ float red[4][2];
    int blk = blockIdx.x;              // 256 = plane(32) x chunk(8)
    int plane = blk >> 3, chunk = blk & 7;
    const float4* p = x1v + (size_t)plane*8192 + chunk*1024;
    float s=0.f, sq=0.f;
    for (int i = threadIdx.x; i < 1024; i += 256) {
        float4 v = p[i];
        s  += v.x+v.y+v.z+v.w;
        sq += v.x*v.x+v.y*v.y+v.z*v.z+v.w*v.w;
    }
    s = waveSum(s); sq = waveSum(sq);
    int wid = threadIdx.x>>6, lane = threadIdx.x&63;
    if (lane == 0) { red[wid][0] = s; red[wid][1] = sq; }
    __syncthreads();
    if (threadIdx.x < 2)
        p2[blk*2+threadIdx.x] = red[0][threadIdx.x]+red[1][threadIdx.x]+red[2][threadIdx.x]+red[3][threadIdx.x];
}

__global__ void k_prep2(const float* __restrict__ p2, const float* __restrict__ g2,
                        const float* __restrict__ b2, float* __restrict__ stats) {
    __shared__ float sm[16];
    int tid = threadIdx.x;
    if (tid < 16) {
        int c = tid & 7, q = tid >> 3;
        float s = 0.f;
        for (int b=0;b<4;++b)
            for (int ch=0;ch<8;++ch)
                s += p2[((b*8+c)*8+ch)*2 + q];
        sm[tid] = s;
    }
    __syncthreads();
    if (tid < 8) {
        float cnt = fmaxf(stats[0], 1.f);
        float mean = sm[tid] / cnt;
        float var  = sm[8+tid] / cnt - mean*mean;
        float s = g2[tid] * rsqrtf(var + BNEPS);
        stats[10+tid] = s; stats[18+tid] = b2[tid] - mean*s;
    }
}

// -------- stage 2: wave-per-output; BN2+LReLU+mask, conv (8->16), pool/8 -> x2 --------
__global__ void k_stage2(const float* __restrict__ x1, const unsigned char* __restrict__ mask32,
                         const float* __restrict__ wc2, const float* __restrict__ stats,
                         float* __restrict__ x2) {
    int t = blockIdx.x * 4 + (threadIdx.x >> 6);   // output id [0, 32768)
    int lane = threadIdx.x & 63;
    int r = t & 511, bo = t >> 9;
    int o = bo & 15, b = bo >> 4;
    int d8 = r >> 6, h8 = (r >> 3) & 7, w8 = r & 7;
    int dd = lane >> 4, hh = (lane >> 2) & 3, ww = lane & 3;   // cell of 4^3 field
    int s32 = ((d8*4+dd) << 10) + ((h8*4+hh) << 5) + (w8*4+ww);
    const float* xb = x1 + (size_t)b*8*32768;
    float wreg = wc2[o*64 + lane];                 // full weight slice for this o
    float m = mask32[b*32768 + s32] ? 1.f : 0.f;
    int widx = (dd&1)*4 + (hh&1)*2 + (ww&1);
    float acc = 0.f;
#pragma unroll
    for (int c=0;c<8;++c) {
        float v = xb[c*32768 + s32];
        float tt = v*stats[10+c] + stats[18+c];
        tt = (tt >= 0.f) ? tt : LEAK*tt;
        acc += tt * __shfl(wreg, c*8 + widx, 64);
    }
    acc = waveSum(acc * m);
    if (lane == 0) x2[t] = acc * 0.125f;
}

// -------- stage-3 stats partials --------
__global__ void k_s3stats(const float* __restrict__ x2, float* __restrict__ p3) {
    __shared__ float red[4][2];
    const float* p = x2 + (size_t)blockIdx.x * 512;   // 64 planes
    float s=0.f, sq=0.f;
    for (int i = threadIdx.x; i < 512; i += 256) { float v = p[i]; s += v; sq += v*v; }
    s = waveSum(s); sq = waveSum(sq);
    int wid = threadIdx.x>>6, lane = threadIdx.x&63;
    if (lane == 0) { red[wid][0] = s; red[wid][1] = sq; }
    __syncthreads();
    if (threadIdx.x < 2)
        p3[blockIdx.x*2+threadIdx.x] = red[0][threadIdx.x]+red[1][threadIdx.x]+red[2][threadIdx.x]+red[3][threadIdx.x];
}

__global__ void k_prep3(const float* __restrict__ p3, const float* __restrict__ g3,
                        const float* __restrict__ b3, float* __restrict__ stats) {
    __shared__ float sm[32];
    int tid = threadIdx.x;
    if (tid < 32) {
        int c = tid & 15, q = tid >> 4;
        float s = 0.f;
        for (int b=0;b<4;++b) s += p3[(b*16+c)*2 + q];
        sm[tid] = s;
    }
    __syncthreads();
    if (tid < 16) {
        float cnt = fmaxf(stats[1], 1.f);
        float mean = sm[tid] / cnt;
        float var  = sm[16+tid] / cnt - mean*mean;
        float s = g3[tid] * rsqrtf(var + BNEPS);
        stats[26+tid] = s; stats[42+tid] = b3[tid] - mean*s;
    }
}

// -------- stage 3: wave-per-output; BN3+LReLU+mask, conv (16->32), pool/8 -> x3 --------
__global__ void k_stage3(const float* __restrict__ x2, const unsigned char* __restrict__ mask8,
                         const float* __restrict__ wc3, const float* __restrict__ stats,
                         float* __restrict__ x3) {
    int t = blockIdx.x * 4 + (threadIdx.x >> 6);   // output id [0, 1024)
    int lane = threadIdx.x & 63;
    int r = t & 7, bo = t >> 3;
    int o = bo & 31, b = bo >> 5;
    int d2 = (r >> 2) & 1, h2 = (r >> 1) & 1, w2 = r & 1;
    int dd = lane >> 4, hh = (lane >> 2) & 3, ww = lane & 3;
    int s8 = (d2*4+dd)*64 + (h2*4+hh)*8 + (w2*4+ww);
    const float* xb = x2 + (size_t)b*16*512;
    float w0r = wc3[o*128 + lane];                 // weights [c<8][widx]
    float w1r = wc3[o*128 + 64 + lane];            // weights [c>=8][widx]
    float m = mask8[b*512 + s8] ? 1.f : 0.f;
    int widx = (dd&1)*4 + (hh&1)*2 + (ww&1);
    float acc = 0.f;
#pragma unroll
    for (int c=0;c<8;++c) {
        float v = xb[c*512 + s8];
        float tt = v*stats[26+c] + stats[42+c];
        tt = (tt >= 0.f) ? tt : LEAK*tt;
        acc += tt * __shfl(w0r, c*8 + widx, 64);
    }
#pragma unroll
    for (int c=8;c<16;++c) {
        float v = xb[c*512 + s8];
        float tt = v*stats[26+c] + stats[42+c];
        tt = (tt >= 0.f) ? tt : LEAK*tt;
        acc += tt * __shfl(w1r, (c-8)*8 + widx, 64);
    }
    acc = waveSum(acc * m);
    if (lane == 0) x3[t] = acc * 0.125f;
}

// -------- final linear: wave-per-output (4,256)@(256,64)^T + blin --------
__global__ void k_linear(const float* __restrict__ x3, const float* __restrict__ wlin,
                         const float* __restrict__ blin, float* __restrict__ out) {
    int t = blockIdx.x * 4 + (threadIdx.x >> 6);   // [0,256) = b*64+j
    int lane = threadIdx.x & 63;
    int b = t >> 6, j = t & 63;
    const float* xb = x3 + b*256;
    const float* wj = wlin + j*256;
    float acc = 0.f;
#pragma unroll
    for (int k=0;k<4;++k) acc += xb[k*64+lane] * wj[k*64+lane];
    acc = waveSum(acc);
    if (lane == 0) out[t] = acc + blin[j];
}

extern "C" void kernel_launch(void* const* d_in, const int* in_sizes, int n_in,
                              void* d_out, int out_size, void* d_ws, size_t ws_size,
                              hipStream_t stream) {
    const float* pc   = (const float*)d_in[0];
    const float* w0   = (const float*)d_in[1];
    const float* g1   = (const float*)d_in[2];
    const float* b1   = (const float*)d_in[3];
    const float* wc1  = (const float*)d_in[4];
    const float* g2   = (const float*)d_in[5];
    const float* b2   = (const float*)d_in[6];
    const float* wc2  = (const float*)d_in[7];
    const float* g3   = (const float*)d_in[8];
    const float* b3   = (const float*)d_in[9];
    const float* wc3  = (const float*)d_in[10];
    const float* wlin = (const float*)d_in[11];
    const float* blin = (const float*)d_in[12];
    float* out = (float*)d_out;

    char* ws = (char*)d_ws;
    float*         dense    = (float*)(ws + OFF_DENSE);
    unsigned*      maskbits = (unsigned*)(ws + OFF_MASKBITS);
    float*         x1       = (float*)(ws + OFF_X1);
    unsigned char* mask32   = (unsigned char*)(ws + OFF_MASK32);
    unsigned char* mask8    = (unsigned char*)(ws + OFF_MASK8);
    float*         stats    = (float*)(ws + OFF_STATS);
    float*         p1       = (float*)(ws + OFF_P1);
    float*         p2       = (float*)(ws + OFF_P2);
    float*         p3       = (float*)(ws + OFF_P3);
    unsigned*      nblk     = (unsigned*)(ws + OFF_NBLK);
    unsigned*      list     = (unsigned*)(ws + OFF_LIST);
    float4*        x0l      = (float4*)(ws + OFF_X0L);
    float*         x2       = (float*)(ws + OFF_X2);
    float*         x3       = (float*)(ws + OFF_X3);

    int n = in_sizes[0] / 5;
    int nb = (n + 255) / 256;

    (void)hipMemsetAsync(ws, 0, ZERO_BYTES, stream);
    k_scatter<<<nb, 256, 0, stream>>>(pc, dense, maskbits, n);
    k_conv0<<<dim3(16,16,64), 512, 0, stream>>>(dense, maskbits, w0, nblk, list, x0l, mask32);
    k_stats1<<<256, 256, 0, stream>>>(x0l, nblk, p1);
    k_prep1<<<1, 256, 0, stream>>>(p1, mask32, mask8, g1, b1, stats);
    k_stage1<<<NTILE*MAXSLOT/256, 256, 0, stream>>>(x0l, list, nblk, wc1, stats, x1);
    k_s2stats<<<256, 256, 0, stream>>>((const float4*)x1, p2);
    k_prep2<<<1, 64, 0, stream>>>(p2, g2, b2, stats);
    k_stage2<<<8192, 256, 0, stream>>>(x1, mask32, wc2, stats, x2);
    k_s3stats<<<64, 256, 0, stream>>>(x2, p3);
    k_prep3<<<1, 64, 0, stream>>>(p3, g3, b3, stats);
    k_stage3<<<256, 256, 0, stream>>>(x2, mask8, wc3, stats, x3);
    k_linear<<<64, 256, 0, stream>>>(x3, wlin, blin, out);
}